// Round 5
// baseline (6085.451 us; speedup 1.0000x reference)
//
#include <hip/hip_runtime.h>
#include <math.h>

#define M_TOK 6272      // B*N = 32*196
#define DIM   768
#define NHEAD 12
#define DHEAD 64
#define MLPD  3072
#define KC    64
#define S768  (768 * 768)

typedef __attribute__((ext_vector_type(8))) short bfrag8;   // 8 bf16 (4 VGPRs)
typedef __attribute__((ext_vector_type(4))) float floatx4;  // MFMA C/D
typedef unsigned short ushort_t;

// ---------------- bf16 split helpers ----------------
static __device__ __forceinline__ unsigned short bf16_rne(float x) {
    unsigned int u = __float_as_uint(x);
    unsigned int r = u + 0x7FFFu + ((u >> 16) & 1u);
    return (unsigned short)(r >> 16);
}

static __device__ __forceinline__ void split1(float v, unsigned short& hi, unsigned short& lo) {
    hi = bf16_rne(v);
    float hif = __uint_as_float((unsigned int)hi << 16);
    lo = bf16_rne(v - hif);
}

// split 8 floats into hi/lo bf16 and store 16B each to LDS
static __device__ __forceinline__ void split8_store(
    const float* v, unsigned short* hdst, unsigned short* ldst)
{
    bfrag8 vh, vl;
    #pragma unroll
    for (int j = 0; j < 8; ++j) {
        unsigned short hi, lo;
        split1(v[j], hi, lo);
        vh[j] = (short)hi;
        vl[j] = (short)lo;
    }
    *(bfrag8*)hdst = vh;
    *(bfrag8*)ldst = vl;
}

// ---------------- block reduce (256-thread blocks, 4 waves) ----------------
static __device__ __forceinline__ float block_reduce_sum(float s) {
    __shared__ float r[4];
    #pragma unroll
    for (int off = 32; off > 0; off >>= 1) s += __shfl_down(s, off);
    int lane = threadIdx.x & 63, wave = threadIdx.x >> 6;
    if (lane == 0) r[wave] = s;
    __syncthreads();
    if (threadIdx.x == 0) r[0] = r[0] + r[1] + r[2] + r[3];
    __syncthreads();
    s = r[0];
    __syncthreads();
    return s;
}

// ---------------- LayerNorm fused with bf16 hi/lo split output ----------------
__global__ __launch_bounds__(256) void ln_split_kernel(
    const float* __restrict__ x, const float* __restrict__ w,
    const float* __restrict__ b, ushort_t* __restrict__ hh,
    ushort_t* __restrict__ hl)
{
    int row = blockIdx.x;
    const float* xr = x + (size_t)row * DIM;
    int t = threadIdx.x;
    float v0 = xr[t], v1 = xr[t + 256], v2 = xr[t + 512];
    float mean = block_reduce_sum(v0 + v1 + v2) * (1.f / 768.f);
    float d0 = v0 - mean, d1 = v1 - mean, d2 = v2 - mean;
    float var = block_reduce_sum(d0 * d0 + d1 * d1 + d2 * d2) * (1.f / 768.f);
    float rstd = rsqrtf(var + 1e-5f);
    size_t base = (size_t)row * DIM;
    float h0 = d0 * rstd * w[t]       + b[t];
    float h1 = d1 * rstd * w[t + 256] + b[t + 256];
    float h2 = d2 * rstd * w[t + 512] + b[t + 512];
    unsigned short hi, lo;
    split1(h0, hi, lo); hh[base + t]       = hi; hl[base + t]       = lo;
    split1(h1, hi, lo); hh[base + t + 256] = hi; hl[base + t + 256] = lo;
    split1(h2, hi, lo); hh[base + t + 512] = hi; hl[base + t + 512] = lo;
}

// ---------------- row ||.||^2 ----------------
__global__ __launch_bounds__(256) void rownorm2_kernel(
    const float* __restrict__ X, float* __restrict__ out)
{
    int row = blockIdx.x;
    const float* xr = X + (size_t)row * DIM;
    int t = threadIdx.x;
    float v0 = xr[t], v1 = xr[t + 256], v2 = xr[t + 512];
    float s = block_reduce_sum(v0 * v0 + v1 * v1 + v2 * v2);
    if (t == 0) out[row] = s;
}

// ---------------- weight transpose + split: W (KxN) -> WhT, WlT (NxK bf16) ----------------
// grid (K/32, N/32, nz); out_z = out + z*2*K*N, hi then lo.
__global__ __launch_bounds__(256) void wsplitT_kernel(
    const float* __restrict__ W0, const float* __restrict__ W1,
    const float* __restrict__ W2, ushort_t* __restrict__ out, int K, int N)
{
    __shared__ float tile[32][33];
    const float* W = (blockIdx.z == 0) ? W0 : (blockIdx.z == 1) ? W1 : W2;
    ushort_t* oh = out + (size_t)blockIdx.z * 2 * K * N;
    ushort_t* ol = oh + (size_t)K * N;
    int kt = blockIdx.x * 32, nt = blockIdx.y * 32;
    int r = threadIdx.x >> 5, c = threadIdx.x & 31;
    #pragma unroll
    for (int i = 0; i < 4; ++i)
        tile[r + i * 8][c] = W[(size_t)(kt + r + i * 8) * N + nt + c];
    __syncthreads();
    #pragma unroll
    for (int i = 0; i < 4; ++i) {
        unsigned short hi, lo;
        split1(tile[c][r + i * 8], hi, lo);
        size_t idx = (size_t)(nt + r + i * 8) * K + kt + c;
        oh[idx] = hi; ol[idx] = lo;
    }
}

// ================= MFMA GEMM cores =================
// Shared fragment/acc layout: tile 128x128, BK=32, 4 waves x (64x64).
// LDS slot order: ((d16>>4)*4 + (k>>3))*16 + (d16&15), 8 bf16/slot.

// ---- variant AB: A pre-split (MxK bf16), B pre-split TRANSPOSED (NxK bf16) ----
static __device__ __forceinline__ void gemm_ab_body(
    const ushort_t* __restrict__ Ah, const ushort_t* __restrict__ Al,
    const ushort_t* __restrict__ BhT, const ushort_t* __restrict__ BlT,
    const float* __restrict__ bias, const float* __restrict__ resid,
    float* __restrict__ C, int N, int K)
{
    __shared__ __align__(16) unsigned short AhL[4096];
    __shared__ __align__(16) unsigned short AlL[4096];
    __shared__ __align__(16) unsigned short BhL[4096];
    __shared__ __align__(16) unsigned short BlL[4096];

    const int tid = threadIdx.x;
    const int bm = blockIdx.y * 128, bn = blockIdx.x * 128;
    const int wave = tid >> 6, lane = tid & 63;
    const int wm = (wave >> 1) * 64, wn = (wave & 1) * 64;
    const int lrow = lane & 15, quad = lane >> 4;

    const int sm  = (tid >> 5) * 16 + 2 * (tid & 7);
    const int skq = (tid >> 3) & 3;
    const size_t arow = (size_t)(bm + sm) * K + skq * 8;
    const size_t brow = (size_t)(bn + sm) * K + skq * 8;

    floatx4 acc[4][4];
    #pragma unroll
    for (int i = 0; i < 4; ++i)
        #pragma unroll
        for (int j = 0; j < 4; ++j) acc[i][j] = floatx4{0.f, 0.f, 0.f, 0.f};

    for (int kt = 0; kt < K; kt += 32) {
        bfrag8 a0h = *(const bfrag8*)(Ah + arow + kt);
        bfrag8 a1h = *(const bfrag8*)(Ah + arow + K + kt);
        bfrag8 a0l = *(const bfrag8*)(Al + arow + kt);
        bfrag8 a1l = *(const bfrag8*)(Al + arow + K + kt);
        bfrag8 b0h = *(const bfrag8*)(BhT + brow + kt);
        bfrag8 b1h = *(const bfrag8*)(BhT + brow + K + kt);
        bfrag8 b0l = *(const bfrag8*)(BlT + brow + kt);
        bfrag8 b1l = *(const bfrag8*)(BlT + brow + K + kt);
        __syncthreads();
        *(bfrag8*)&AhL[16 * tid] = a0h;  *(bfrag8*)&AhL[16 * tid + 8] = a1h;
        *(bfrag8*)&AlL[16 * tid] = a0l;  *(bfrag8*)&AlL[16 * tid + 8] = a1l;
        *(bfrag8*)&BhL[16 * tid] = b0h;  *(bfrag8*)&BhL[16 * tid + 8] = b1h;
        *(bfrag8*)&BlL[16 * tid] = b0l;  *(bfrag8*)&BlL[16 * tid + 8] = b1l;
        __syncthreads();

        bfrag8 afh[4], afl[4], bfh[4], bfl[4];
        #pragma unroll
        for (int mt = 0; mt < 4; ++mt) {
            int base = (((wm >> 4) + mt) * 4 + quad) * 128 + lrow * 8;
            afh[mt] = *(const bfrag8*)&AhL[base];
            afl[mt] = *(const bfrag8*)&AlL[base];
        }
        #pragma unroll
        for (int nt = 0; nt < 4; ++nt) {
            int base = (((wn >> 4) + nt) * 4 + quad) * 128 + lrow * 8;
            bfh[nt] = *(const bfrag8*)&BhL[base];
            bfl[nt] = *(const bfrag8*)&BlL[base];
        }
        #pragma unroll
        for (int mt = 0; mt < 4; ++mt)
            #pragma unroll
            for (int nt = 0; nt < 4; ++nt) {
                acc[mt][nt] = __builtin_amdgcn_mfma_f32_16x16x32_bf16(
                    afh[mt], bfh[nt], acc[mt][nt], 0, 0, 0);
                acc[mt][nt] = __builtin_amdgcn_mfma_f32_16x16x32_bf16(
                    afh[mt], bfl[nt], acc[mt][nt], 0, 0, 0);
                acc[mt][nt] = __builtin_amdgcn_mfma_f32_16x16x32_bf16(
                    afl[mt], bfh[nt], acc[mt][nt], 0, 0, 0);
            }
    }

    #pragma unroll
    for (int mt = 0; mt < 4; ++mt)
        #pragma unroll
        for (int r = 0; r < 4; ++r) {
            int row = bm + wm + mt * 16 + quad * 4 + r;
            #pragma unroll
            for (int nt = 0; nt < 4; ++nt) {
                int col = bn + wn + nt * 16 + lrow;
                float v = acc[mt][nt][r];
                if (bias)  v += bias[col];
                if (resid) v += resid[(size_t)row * N + col];
                C[(size_t)row * N + col] = v;
            }
        }
}

__global__ __launch_bounds__(256) void gemm_ab_kernel(
    const ushort_t* __restrict__ Ah, const ushort_t* __restrict__ Al,
    const ushort_t* __restrict__ BhT, const ushort_t* __restrict__ BlT,
    const float* __restrict__ bias, const float* __restrict__ resid,
    float* __restrict__ C, int N, int K)
{
    gemm_ab_body(Ah, Al, BhT, BlT, bias, resid, C, N, K);
}

__global__ __launch_bounds__(256) void gemm_qkv_ab_kernel(
    const ushort_t* __restrict__ Ah, const ushort_t* __restrict__ Al,
    const ushort_t* __restrict__ wT,     // 3 weights packed: z*2*S768, hi then lo
    float* __restrict__ C0, float* __restrict__ C1, float* __restrict__ C2,
    int N, int K)
{
    const ushort_t* bh = wT + (size_t)blockIdx.z * 2 * S768;
    const ushort_t* bl = bh + S768;
    float* C = (blockIdx.z == 0) ? C0 : (blockIdx.z == 1) ? C1 : C2;
    gemm_ab_body(Ah, Al, bh, bl, nullptr, nullptr, C, N, K);
}

// ---- variant aB32: A pre-split (MxK bf16); B fp32 row-major KxN, split in-kernel ----
// epilogue: act(gelu) optional; output either fp32 C (+resid) or split Ch/Cl.
__global__ __launch_bounds__(256) void gemm_aB32_kernel(
    const ushort_t* __restrict__ Ah, const ushort_t* __restrict__ Al,
    const float* __restrict__ B, const float* __restrict__ bias,
    const float* __restrict__ resid, float* __restrict__ C,
    ushort_t* __restrict__ Ch, ushort_t* __restrict__ Cl,
    int N, int K, int act)
{
    __shared__ __align__(16) unsigned short AhL[4096];
    __shared__ __align__(16) unsigned short AlL[4096];
    __shared__ __align__(16) unsigned short BhL[4096];
    __shared__ __align__(16) unsigned short BlL[4096];

    const int tid = threadIdx.x;
    const int bm = blockIdx.y * 128, bn = blockIdx.x * 128;
    const int wave = tid >> 6, lane = tid & 63;
    const int wm = (wave >> 1) * 64, wn = (wave & 1) * 64;
    const int lrow = lane & 15, quad = lane >> 4;

    const int sm  = (tid >> 5) * 16 + 2 * (tid & 7);
    const int skq = (tid >> 3) & 3;
    const size_t arow = (size_t)(bm + sm) * K + skq * 8;
    const float* Bbase = B + (size_t)(skq * 8) * N + bn + sm;

    floatx4 acc[4][4];
    #pragma unroll
    for (int i = 0; i < 4; ++i)
        #pragma unroll
        for (int j = 0; j < 4; ++j) acc[i][j] = floatx4{0.f, 0.f, 0.f, 0.f};

    for (int kt = 0; kt < K; kt += 32) {
        bfrag8 a0h = *(const bfrag8*)(Ah + arow + kt);
        bfrag8 a1h = *(const bfrag8*)(Ah + arow + K + kt);
        bfrag8 a0l = *(const bfrag8*)(Al + arow + kt);
        bfrag8 a1l = *(const bfrag8*)(Al + arow + K + kt);
        float2 bv[8];
        #pragma unroll
        for (int j = 0; j < 8; ++j)
            bv[j] = *(const float2*)(Bbase + (size_t)(kt + j) * N);

        __syncthreads();
        *(bfrag8*)&AhL[16 * tid] = a0h;  *(bfrag8*)&AhL[16 * tid + 8] = a1h;
        *(bfrag8*)&AlL[16 * tid] = a0l;  *(bfrag8*)&AlL[16 * tid + 8] = a1l;
        {
            float b0v[8] = {bv[0].x, bv[1].x, bv[2].x, bv[3].x,
                            bv[4].x, bv[5].x, bv[6].x, bv[7].x};
            float b1v[8] = {bv[0].y, bv[1].y, bv[2].y, bv[3].y,
                            bv[4].y, bv[5].y, bv[6].y, bv[7].y};
            split8_store(b0v, &BhL[16 * tid], &BlL[16 * tid]);
            split8_store(b1v, &BhL[16 * tid + 8], &BlL[16 * tid + 8]);
        }
        __syncthreads();

        bfrag8 afh[4], afl[4], bfh[4], bfl[4];
        #pragma unroll
        for (int mt = 0; mt < 4; ++mt) {
            int base = (((wm >> 4) + mt) * 4 + quad) * 128 + lrow * 8;
            afh[mt] = *(const bfrag8*)&AhL[base];
            afl[mt] = *(const bfrag8*)&AlL[base];
        }
        #pragma unroll
        for (int nt = 0; nt < 4; ++nt) {
            int base = (((wn >> 4) + nt) * 4 + quad) * 128 + lrow * 8;
            bfh[nt] = *(const bfrag8*)&BhL[base];
            bfl[nt] = *(const bfrag8*)&BlL[base];
        }
        #pragma unroll
        for (int mt = 0; mt < 4; ++mt)
            #pragma unroll
            for (int nt = 0; nt < 4; ++nt) {
                acc[mt][nt] = __builtin_amdgcn_mfma_f32_16x16x32_bf16(
                    afh[mt], bfh[nt], acc[mt][nt], 0, 0, 0);
                acc[mt][nt] = __builtin_amdgcn_mfma_f32_16x16x32_bf16(
                    afh[mt], bfl[nt], acc[mt][nt], 0, 0, 0);
                acc[mt][nt] = __builtin_amdgcn_mfma_f32_16x16x32_bf16(
                    afl[mt], bfh[nt], acc[mt][nt], 0, 0, 0);
            }
    }

    #pragma unroll
    for (int mt = 0; mt < 4; ++mt)
        #pragma unroll
        for (int r = 0; r < 4; ++r) {
            int row = bm + wm + mt * 16 + quad * 4 + r;
            #pragma unroll
            for (int nt = 0; nt < 4; ++nt) {
                int col = bn + wn + nt * 16 + lrow;
                float v = acc[mt][nt][r];
                if (bias) v += bias[col];
                if (act)  v = 0.5f * v * (1.f + erff(v * 0.70710678118654752f));
                size_t idx = (size_t)row * N + col;
                if (Ch) {
                    unsigned short hi, lo;
                    split1(v, hi, lo);
                    Ch[idx] = hi; Cl[idx] = lo;
                } else {
                    if (resid) v += resid[idx];
                    C[idx] = v;
                }
            }
        }
}

// ---------------- small fp32 GEMM (64x768 ct projection) ----------------
static __device__ __forceinline__ void gemm_body(
    const float* __restrict__ A, const float* __restrict__ B,
    const float* __restrict__ bias, const float* __restrict__ resid,
    float* __restrict__ C, int M, int N, int K, int act)
{
    __shared__ float As[16][128];
    __shared__ float Bs[16][64];
    const int bm = blockIdx.y * 128;
    const int bn = blockIdx.x * 64;
    const int tid = threadIdx.x;
    const int tx = tid & 15;
    const int ty = tid >> 4;
    float acc[8][4];
    #pragma unroll
    for (int i = 0; i < 8; ++i)
        #pragma unroll
        for (int j = 0; j < 4; ++j) acc[i][j] = 0.f;

    const int a_row = tid >> 1;
    const int a_kp  = (tid & 1) * 8;
    const int b_k   = tid >> 4;
    const int b_c   = (tid & 15) * 4;

    for (int k0 = 0; k0 < K; k0 += 16) {
        int grow = bm + a_row;
        float4 a0, a1;
        if (grow < M) {
            const float* ap = A + (size_t)grow * K + (k0 + a_kp);
            a0 = *(const float4*)ap;
            a1 = *(const float4*)(ap + 4);
        } else {
            a0 = make_float4(0.f, 0.f, 0.f, 0.f); a1 = a0;
        }
        float4 bvv = *(const float4*)(B + (size_t)(k0 + b_k) * N + (bn + b_c));
        __syncthreads();
        As[a_kp + 0][a_row] = a0.x; As[a_kp + 1][a_row] = a0.y;
        As[a_kp + 2][a_row] = a0.z; As[a_kp + 3][a_row] = a0.w;
        As[a_kp + 4][a_row] = a1.x; As[a_kp + 5][a_row] = a1.y;
        As[a_kp + 6][a_row] = a1.z; As[a_kp + 7][a_row] = a1.w;
        *(float4*)&Bs[b_k][b_c] = bvv;
        __syncthreads();
        #pragma unroll
        for (int kk = 0; kk < 16; ++kk) {
            float4 af0 = *(const float4*)&As[kk][ty * 8];
            float4 af1 = *(const float4*)&As[kk][ty * 8 + 4];
            float4 bf  = *(const float4*)&Bs[kk][tx * 4];
            float a_[8] = {af0.x, af0.y, af0.z, af0.w, af1.x, af1.y, af1.z, af1.w};
            float b_[4] = {bf.x, bf.y, bf.z, bf.w};
            #pragma unroll
            for (int i = 0; i < 8; ++i)
                #pragma unroll
                for (int j = 0; j < 4; ++j)
                    acc[i][j] = fmaf(a_[i], b_[j], acc[i][j]);
        }
    }
    #pragma unroll
    for (int i = 0; i < 8; ++i) {
        int row = bm + ty * 8 + i;
        if (row < M) {
            #pragma unroll
            for (int j = 0; j < 4; ++j) {
                int col = bn + tx * 4 + j;
                float v = acc[i][j];
                if (bias)  v += bias[col];
                if (act)   v = 0.5f * v * (1.f + erff(v * 0.70710678118654752f));
                if (resid) v += resid[(size_t)row * N + col];
                C[(size_t)row * N + col] = v;
            }
        }
    }
}

__global__ __launch_bounds__(256) void gemm_kernel(
    const float* __restrict__ A, const float* __restrict__ B,
    const float* __restrict__ bias, const float* __restrict__ resid,
    float* __restrict__ C, int M, int N, int K, int act)
{
    gemm_body(A, B, bias, resid, C, M, N, K, act);
}

// ---------------- attention: block = (qhalf, head, batch); split o output ----------------
__global__ __launch_bounds__(256) void attn_kernel(
    const float* __restrict__ q, const float* __restrict__ k,
    const float* __restrict__ v, ushort_t* __restrict__ oh,
    ushort_t* __restrict__ ol)
{
    __shared__ float Ks[196][65];
    int qh = blockIdx.x;
    int h  = blockIdx.y;
    int b  = blockIdx.z;
    const size_t bbase = (size_t)b * 196 * DIM + (size_t)h * DHEAD;
    for (int e = threadIdx.x; e < 196 * 64; e += 256) {
        int n = e >> 6, d = e & 63;
        Ks[n][d] = k[bbase + (size_t)n * DIM + d];
    }
    __syncthreads();
    int wave = threadIdx.x >> 6, lane = threadIdx.x & 63;
    const float scale = 0.125f;
    for (int l = wave; l < 98; l += 4) {
        int qi = qh * 98 + l;
        float qv = q[bbase + (size_t)qi * DIM + lane];
        float s0 = 0.f, s1 = 0.f, s2 = 0.f, s3 = 0.f;
        #pragma unroll 8
        for (int d = 0; d < 64; ++d) {
            float qd = __shfl(qv, d);
            s0 = fmaf(qd, Ks[lane][d], s0);
            s1 = fmaf(qd, Ks[lane + 64][d], s1);
            s2 = fmaf(qd, Ks[lane + 128][d], s2);
            if (lane < 4) s3 = fmaf(qd, Ks[lane + 192][d], s3);
        }
        s0 *= scale; s1 *= scale; s2 *= scale; s3 *= scale;
        float m = fmaxf(fmaxf(s0, s1), s2);
        if (lane < 4) m = fmaxf(m, s3);
        #pragma unroll
        for (int off = 32; off > 0; off >>= 1) m = fmaxf(m, __shfl_xor(m, off));
        float e0 = expf(s0 - m), e1 = expf(s1 - m), e2 = expf(s2 - m);
        float e3 = (lane < 4) ? expf(s3 - m) : 0.f;
        float lsum = e0 + e1 + e2 + e3;
        #pragma unroll
        for (int off = 32; off > 0; off >>= 1) lsum += __shfl_xor(lsum, off);
        float inv = 1.f / lsum;
        float p0 = e0 * inv, p1 = e1 * inv, p2 = e2 * inv, p3 = e3 * inv;
        const float* vb = v + bbase + lane;
        float o0 = 0.f, o1 = 0.f, o2 = 0.f, o3 = 0.f;
        #pragma unroll 8
        for (int j = 0; j < 64; ++j) {
            o0 = fmaf(__shfl(p0, j), vb[(size_t)j * DIM], o0);
            o1 = fmaf(__shfl(p1, j), vb[(size_t)(j + 64) * DIM], o1);
            o2 = fmaf(__shfl(p2, j), vb[(size_t)(j + 128) * DIM], o2);
        }
        #pragma unroll
        for (int j = 0; j < 4; ++j)
            o3 = fmaf(__shfl(p3, j), vb[(size_t)(j + 192) * DIM], o3);
        float ov = (o0 + o1) + (o2 + o3);
        unsigned short hi, lo;
        split1(ov, hi, lo);
        oh[bbase + (size_t)qi * DIM + lane] = hi;
        ol[bbase + (size_t)qi * DIM + lane] = lo;
    }
}

// ---------------- k-means ----------------
__global__ __launch_bounds__(256) void transpose_ct(
    const float* __restrict__ C, float* __restrict__ CT)
{
    int i = blockIdx.x * 256 + threadIdx.x;
    if (i < DIM * KC) {
        int d = i / KC, c = i % KC;
        CT[i] = C[(size_t)c * DIM + d];
    }
}

__global__ __launch_bounds__(256) void assign_kernel(
    const float* __restrict__ P, const float* __restrict__ CT,
    const float* __restrict__ cn2, const float* __restrict__ pn2,
    int* __restrict__ labels)
{
    __shared__ float cts[256 * KC];
    int wave = threadIdx.x >> 6, lane = threadIdx.x & 63;
    int p = blockIdx.x * 4 + wave;
    float acc = 0.f;
    for (int ch = 0; ch < 3; ++ch) {
        __syncthreads();
        for (int e = threadIdx.x; e < 256 * KC / 4; e += 256)
            ((float4*)cts)[e] = ((const float4*)(CT + (size_t)ch * 256 * KC))[e];
        __syncthreads();
        const float* pr = P + (size_t)p * DIM + ch * 256;
        float a0 = 0.f, a1 = 0.f, a2 = 0.f, a3 = 0.f;
        #pragma unroll 4
        for (int kk = 0; kk < 256; kk += 4) {
            a0 = fmaf(pr[kk],     cts[(kk)     * KC + lane], a0);
            a1 = fmaf(pr[kk + 1], cts[(kk + 1) * KC + lane], a1);
            a2 = fmaf(pr[kk + 2], cts[(kk + 2) * KC + lane], a2);
            a3 = fmaf(pr[kk + 3], cts[(kk + 3) * KC + lane], a3);
        }
        acc += (a0 + a1) + (a2 + a3);
    }
    float dist = (pn2[p] - 2.f * acc) + cn2[lane];
    int idx = lane;
    #pragma unroll
    for (int off = 32; off > 0; off >>= 1) {
        float d2 = __shfl_xor(dist, off);
        int   i2 = __shfl_xor(idx, off);
        if (d2 < dist || (d2 == dist && i2 < idx)) { dist = d2; idx = i2; }
    }
    if (lane == 0) labels[p] = idx;
}

// counting sort: one block. cnt[c], off[c], stable order[] of point indices.
__global__ __launch_bounds__(256) void order_kernel(
    const int* __restrict__ labels, int* __restrict__ cnt,
    int* __restrict__ off, int* __restrict__ order)
{
    __shared__ int labs[M_TOK];
    __shared__ int hist[4][KC];
    __shared__ int wstart[4][KC];
    int tid = threadIdx.x;
    for (int p = tid; p < M_TOK; p += 256) labs[p] = labels[p];
    int wave = tid >> 6, lane = tid & 63;
    __syncthreads();
    const int base = wave * (M_TOK / 4);
    int h = 0;
    for (int i = 0; i < M_TOK / 4; ++i) h += (labs[base + i] == lane);
    hist[wave][lane] = h;
    __syncthreads();
    if (tid == 0) {
        int run = 0;
        for (int c = 0; c < KC; ++c) {
            int h0 = hist[0][c], h1 = hist[1][c], h2 = hist[2][c], h3 = hist[3][c];
            cnt[c] = h0 + h1 + h2 + h3;
            off[c] = run;
            wstart[0][c] = run;
            wstart[1][c] = run + h0;
            wstart[2][c] = run + h0 + h1;
            wstart[3][c] = run + h0 + h1 + h2;
            run += h0 + h1 + h2 + h3;
        }
    }
    __syncthreads();
    int pos = wstart[wave][lane];
    for (int i = 0; i < M_TOK / 4; ++i) {
        if (labs[base + i] == lane) order[pos++] = base + i;
    }
}

__global__ __launch_bounds__(768) void update_gather_kernel(
    const float* __restrict__ P, const int* __restrict__ order,
    const int* __restrict__ cnt, const int* __restrict__ off,
    const float* __restrict__ cin, float* __restrict__ cout)
{
    __shared__ int rows[M_TOK];
    int c = blockIdx.x;
    int n = cnt[c], o = off[c];
    int d = threadIdx.x;
    for (int i = d; i < n; i += 768) rows[i] = order[o + i];
    __syncthreads();
    float a0 = 0.f, a1 = 0.f, a2 = 0.f, a3 = 0.f;
    int i = 0;
    for (; i + 4 <= n; i += 4) {
        a0 += P[(size_t)rows[i]     * DIM + d];
        a1 += P[(size_t)rows[i + 1] * DIM + d];
        a2 += P[(size_t)rows[i + 2] * DIM + d];
        a3 += P[(size_t)rows[i + 3] * DIM + d];
    }
    for (; i < n; ++i) a0 += P[(size_t)rows[i] * DIM + d];
    float s = (a0 + a1) + (a2 + a3);
    cout[(size_t)c * DIM + d] = (n > 0) ? (s / (float)n) : cin[(size_t)c * DIM + d];
}

__global__ __launch_bounds__(256) void gather_kernel(
    const float* __restrict__ cproj, const int* __restrict__ labels,
    float* __restrict__ out)
{
    int i = blockIdx.x * 256 + threadIdx.x;
    int p = i / DIM, d = i - p * DIM;
    out[i] = cproj[(size_t)labels[p] * DIM + d];
}

// ---------------- host ----------------
extern "C" void kernel_launch(void* const* d_in, const int* in_sizes, int n_in,
                              void* d_out, int out_size, void* d_ws, size_t ws_size,
                              hipStream_t stream)
{
    const float* x    = (const float*)d_in[0];
    const float* ln1w = (const float*)d_in[1];
    const float* ln1b = (const float*)d_in[2];
    const float* wq   = (const float*)d_in[3];
    const float* wk   = (const float*)d_in[4];
    const float* wv   = (const float*)d_in[5];
    const float* wo   = (const float*)d_in[6];
    const float* bo   = (const float*)d_in[7];
    const float* ln2w = (const float*)d_in[8];
    const float* ln2b = (const float*)d_in[9];
    const float* w1   = (const float*)d_in[10];
    const float* b1   = (const float*)d_in[11];
    const float* w2   = (const float*)d_in[12];
    const float* b2   = (const float*)d_in[13];
    const float* ctw  = (const float*)d_in[14];
    const float* ctb  = (const float*)d_in[15];

    const size_t M768 = (size_t)M_TOK * DIM;      // 4,816,896 elements
    float* ws    = (float*)d_ws;
    float* xbuf  = ws;
    float* qbuf  = xbuf + M768;
    float* kbuf  = qbuf + M768;
    float* vbuf  = kbuf + M768;
    float* obuf  = vbuf + M768;
    float* cA    = obuf + M768;
    float* cB    = cA + (size_t)KC * DIM;
    float* CT    = cB + (size_t)KC * DIM;
    float* cproj = CT + (size_t)KC * DIM;
    float* cn2   = cproj + (size_t)KC * DIM;
    float* pn2   = cn2 + KC;
    int*  labels = (int*)(pn2 + M_TOK);
    int*  cnt    = labels + M_TOK;
    int*  coff   = cnt + KC;
    int*  order  = coff + KC;

    // bf16 split aliases (all within the R1-proven footprint):
    ushort_t* hh    = (ushort_t*)d_out;           // h hi   (M x 768)
    ushort_t* hl    = hh + M768;                  // h lo
    ushort_t* woT   = (ushort_t*)d_out;           // wo^T split (after h consumed)
    ushort_t* wqkvT = (ushort_t*)obuf;            // 3x 768x768 hi/lo (7.1 MB)
    ushort_t* oh    = (ushort_t*)obuf;            // o hi (after wqkvT consumed)
    ushort_t* ol    = oh + M768;                  // o lo
    ushort_t* m1h   = (ushort_t*)qbuf;            // m1 hi (M x 3072) -> q+k region
    ushort_t* m1l   = m1h + (size_t)M_TOK * MLPD; // m1 lo -> v+o region

    hipMemcpyAsync(xbuf, x, M768 * sizeof(float), hipMemcpyDeviceToDevice, stream);

    dim3 blk(256);
    dim3 gN768(DIM / 128, M_TOK / 128);        // 6 x 49
    dim3 gN3072(MLPD / 128, M_TOK / 128);      // 24 x 49
    dim3 gqkv(DIM / 128, M_TOK / 128, 3);      // 6 x 49 x 3
    dim3 gsplit3(DIM / 32, DIM / 32, 3);       // 24 x 24 x 3
    dim3 gsplit1(DIM / 32, DIM / 32, 1);

    for (int d = 0; d < 4; ++d) {
        size_t w768 = (size_t)d * DIM * DIM;
        ln_split_kernel<<<M_TOK, blk, 0, stream>>>(xbuf, ln1w + d * DIM, ln1b + d * DIM, hh, hl);
        wsplitT_kernel<<<gsplit3, blk, 0, stream>>>(wq + w768, wk + w768, wv + w768,
                                                    wqkvT, DIM, DIM);
        gemm_qkv_ab_kernel<<<gqkv, blk, 0, stream>>>(hh, hl, wqkvT, qbuf, kbuf, vbuf, DIM, DIM);
        attn_kernel<<<dim3(2, NHEAD, 32), blk, 0, stream>>>(qbuf, kbuf, vbuf, oh, ol);
        wsplitT_kernel<<<gsplit1, blk, 0, stream>>>(wo + w768, wo + w768, wo + w768,
                                                    woT, DIM, DIM);
        gemm_ab_kernel<<<gN768, blk, 0, stream>>>(oh, ol, woT, woT + S768,
                                                  bo + d * DIM, xbuf, xbuf, DIM, DIM);
        ln_split_kernel<<<M_TOK, blk, 0, stream>>>(xbuf, ln2w + d * DIM, ln2b + d * DIM, hh, hl);
        gemm_aB32_kernel<<<gN3072, blk, 0, stream>>>(hh, hl, w1 + (size_t)d * DIM * MLPD,
                                                     b1 + d * MLPD, nullptr, nullptr,
                                                     m1h, m1l, MLPD, DIM, 1);
        gemm_aB32_kernel<<<gN768, blk, 0, stream>>>(m1h, m1l, w2 + (size_t)d * MLPD * DIM,
                                                    b2 + d * DIM, xbuf, xbuf,
                                                    nullptr, nullptr, DIM, MLPD, 0);
    }

    // ---- k-means on xbuf ----
    rownorm2_kernel<<<M_TOK, blk, 0, stream>>>(xbuf, pn2);
    hipMemcpyAsync(cA, xbuf, (size_t)KC * DIM * sizeof(float),
                   hipMemcpyDeviceToDevice, stream);
    float* cin = cA; float* cout = cB;
    for (int it = 0; it < 10; ++it) {
        rownorm2_kernel<<<KC, blk, 0, stream>>>(cin, cn2);
        transpose_ct<<<(KC * DIM + 255) / 256, blk, 0, stream>>>(cin, CT);
        assign_kernel<<<M_TOK / 4, blk, 0, stream>>>(xbuf, CT, cn2, pn2, labels);
        order_kernel<<<1, blk, 0, stream>>>(labels, cnt, coff, order);
        update_gather_kernel<<<KC, dim3(768), 0, stream>>>(xbuf, order, cnt, coff, cin, cout);
        float* t = cin; cin = cout; cout = t;
    }
    rownorm2_kernel<<<KC, blk, 0, stream>>>(cin, cn2);
    transpose_ct<<<(KC * DIM + 255) / 256, blk, 0, stream>>>(cin, CT);
    assign_kernel<<<M_TOK / 4, blk, 0, stream>>>(xbuf, CT, cn2, pn2, labels);

    gemm_kernel<<<dim3(DIM / 64, 1), blk, 0, stream>>>(cin, ctw, ctb, nullptr, cproj,
                                                       KC, DIM, DIM, 0);
    gather_kernel<<<(M_TOK * DIM) / 256, blk, 0, stream>>>(cproj, labels, (float*)d_out);
}

// Round 6
// 5154.745 us; speedup vs baseline: 1.1806x; 1.1806x over previous
//
#include <hip/hip_runtime.h>
#include <math.h>

#define M_TOK 6272      // B*N = 32*196
#define DIM   768
#define NHEAD 12
#define DHEAD 64
#define MLPD  3072
#define KC    64
#define S768  (768 * 768)

typedef __attribute__((ext_vector_type(8))) short bfrag8;   // 8 bf16 (4 VGPRs)
typedef __attribute__((ext_vector_type(4))) float floatx4;  // MFMA C/D
typedef unsigned short ushort_t;

// ---------------- bf16 split helpers ----------------
static __device__ __forceinline__ unsigned short bf16_rne(float x) {
    unsigned int u = __float_as_uint(x);
    unsigned int r = u + 0x7FFFu + ((u >> 16) & 1u);
    return (unsigned short)(r >> 16);
}

static __device__ __forceinline__ void split1(float v, unsigned short& hi, unsigned short& lo) {
    hi = bf16_rne(v);
    float hif = __uint_as_float((unsigned int)hi << 16);
    lo = bf16_rne(v - hif);
}

static __device__ __forceinline__ void split8_store(
    const float* v, unsigned short* hdst, unsigned short* ldst)
{
    bfrag8 vh, vl;
    #pragma unroll
    for (int j = 0; j < 8; ++j) {
        unsigned short hi, lo;
        split1(v[j], hi, lo);
        vh[j] = (short)hi;
        vl[j] = (short)lo;
    }
    *(bfrag8*)hdst = vh;
    *(bfrag8*)ldst = vl;
}

// ---------------- block reduce (256-thread blocks, 4 waves) ----------------
static __device__ __forceinline__ float block_reduce_sum(float s) {
    __shared__ float r[4];
    #pragma unroll
    for (int off = 32; off > 0; off >>= 1) s += __shfl_down(s, off);
    int lane = threadIdx.x & 63, wave = threadIdx.x >> 6;
    if (lane == 0) r[wave] = s;
    __syncthreads();
    if (threadIdx.x == 0) r[0] = r[0] + r[1] + r[2] + r[3];
    __syncthreads();
    s = r[0];
    __syncthreads();
    return s;
}

// ---------------- LayerNorm fused with bf16 hi/lo split output ----------------
__global__ __launch_bounds__(256) void ln_split_kernel(
    const float* __restrict__ x, const float* __restrict__ w,
    const float* __restrict__ b, ushort_t* __restrict__ hh,
    ushort_t* __restrict__ hl)
{
    int row = blockIdx.x;
    const float* xr = x + (size_t)row * DIM;
    int t = threadIdx.x;
    float v0 = xr[t], v1 = xr[t + 256], v2 = xr[t + 512];
    float mean = block_reduce_sum(v0 + v1 + v2) * (1.f / 768.f);
    float d0 = v0 - mean, d1 = v1 - mean, d2 = v2 - mean;
    float var = block_reduce_sum(d0 * d0 + d1 * d1 + d2 * d2) * (1.f / 768.f);
    float rstd = rsqrtf(var + 1e-5f);
    size_t base = (size_t)row * DIM;
    float h0 = d0 * rstd * w[t]       + b[t];
    float h1 = d1 * rstd * w[t + 256] + b[t + 256];
    float h2 = d2 * rstd * w[t + 512] + b[t + 512];
    unsigned short hi, lo;
    split1(h0, hi, lo); hh[base + t]       = hi; hl[base + t]       = lo;
    split1(h1, hi, lo); hh[base + t + 256] = hi; hl[base + t + 256] = lo;
    split1(h2, hi, lo); hh[base + t + 512] = hi; hl[base + t + 512] = lo;
}

// ---------------- row ||.||^2 ----------------
__global__ __launch_bounds__(256) void rownorm2_kernel(
    const float* __restrict__ X, float* __restrict__ out)
{
    int row = blockIdx.x;
    const float* xr = X + (size_t)row * DIM;
    int t = threadIdx.x;
    float v0 = xr[t], v1 = xr[t + 256], v2 = xr[t + 512];
    float s = block_reduce_sum(v0 * v0 + v1 * v1 + v2 * v2);
    if (t == 0) out[row] = s;
}

// ---------------- weight transpose + split: W (KxN) -> WhT, WlT (NxK bf16) ----------------
__global__ __launch_bounds__(256) void wsplitT_kernel(
    const float* __restrict__ W0, const float* __restrict__ W1,
    const float* __restrict__ W2, ushort_t* __restrict__ out, int K, int N)
{
    __shared__ float tile[32][33];
    const float* W = (blockIdx.z == 0) ? W0 : (blockIdx.z == 1) ? W1 : W2;
    ushort_t* oh = out + (size_t)blockIdx.z * 2 * K * N;
    ushort_t* ol = oh + (size_t)K * N;
    int kt = blockIdx.x * 32, nt = blockIdx.y * 32;
    int r = threadIdx.x >> 5, c = threadIdx.x & 31;
    #pragma unroll
    for (int i = 0; i < 4; ++i)
        tile[r + i * 8][c] = W[(size_t)(kt + r + i * 8) * N + nt + c];
    __syncthreads();
    #pragma unroll
    for (int i = 0; i < 4; ++i) {
        unsigned short hi, lo;
        split1(tile[c][r + i * 8], hi, lo);
        size_t idx = (size_t)(nt + r + i * 8) * K + kt + c;
        oh[idx] = hi; ol[idx] = lo;
    }
}

// ================= MFMA GEMM cores =================
// Tile 128x128, BK=32, 4 waves x (64x64).
// LDS slot order: ((d16>>4)*4 + (k>>3))*16 + (d16&15), 8 bf16/slot.

// ---- variant AB: A pre-split (MxK bf16), B pre-split TRANSPOSED (NxK bf16) ----
// epilogue: fp32 C (+bias,+resid) or split Ch/Cl (+bias).
static __device__ __forceinline__ void gemm_ab_body(
    const ushort_t* __restrict__ Ah, const ushort_t* __restrict__ Al,
    const ushort_t* __restrict__ BhT, const ushort_t* __restrict__ BlT,
    const float* __restrict__ bias, const float* __restrict__ resid,
    float* __restrict__ C, ushort_t* __restrict__ Ch, ushort_t* __restrict__ Cl,
    int N, int K)
{
    __shared__ __align__(16) unsigned short AhL[4096];
    __shared__ __align__(16) unsigned short AlL[4096];
    __shared__ __align__(16) unsigned short BhL[4096];
    __shared__ __align__(16) unsigned short BlL[4096];

    const int tid = threadIdx.x;
    const int bm = blockIdx.y * 128, bn = blockIdx.x * 128;
    const int wave = tid >> 6, lane = tid & 63;
    const int wm = (wave >> 1) * 64, wn = (wave & 1) * 64;
    const int lrow = lane & 15, quad = lane >> 4;

    const int sm  = (tid >> 5) * 16 + 2 * (tid & 7);
    const int skq = (tid >> 3) & 3;
    const size_t arow = (size_t)(bm + sm) * K + skq * 8;
    const size_t brow = (size_t)(bn + sm) * K + skq * 8;

    floatx4 acc[4][4];
    #pragma unroll
    for (int i = 0; i < 4; ++i)
        #pragma unroll
        for (int j = 0; j < 4; ++j) acc[i][j] = floatx4{0.f, 0.f, 0.f, 0.f};

    for (int kt = 0; kt < K; kt += 32) {
        bfrag8 a0h = *(const bfrag8*)(Ah + arow + kt);
        bfrag8 a1h = *(const bfrag8*)(Ah + arow + K + kt);
        bfrag8 a0l = *(const bfrag8*)(Al + arow + kt);
        bfrag8 a1l = *(const bfrag8*)(Al + arow + K + kt);
        bfrag8 b0h = *(const bfrag8*)(BhT + brow + kt);
        bfrag8 b1h = *(const bfrag8*)(BhT + brow + K + kt);
        bfrag8 b0l = *(const bfrag8*)(BlT + brow + kt);
        bfrag8 b1l = *(const bfrag8*)(BlT + brow + K + kt);
        __syncthreads();
        *(bfrag8*)&AhL[16 * tid] = a0h;  *(bfrag8*)&AhL[16 * tid + 8] = a1h;
        *(bfrag8*)&AlL[16 * tid] = a0l;  *(bfrag8*)&AlL[16 * tid + 8] = a1l;
        *(bfrag8*)&BhL[16 * tid] = b0h;  *(bfrag8*)&BhL[16 * tid + 8] = b1h;
        *(bfrag8*)&BlL[16 * tid] = b0l;  *(bfrag8*)&BlL[16 * tid + 8] = b1l;
        __syncthreads();

        bfrag8 afh[4], afl[4], bfh[4], bfl[4];
        #pragma unroll
        for (int mt = 0; mt < 4; ++mt) {
            int base = (((wm >> 4) + mt) * 4 + quad) * 128 + lrow * 8;
            afh[mt] = *(const bfrag8*)&AhL[base];
            afl[mt] = *(const bfrag8*)&AlL[base];
        }
        #pragma unroll
        for (int nt = 0; nt < 4; ++nt) {
            int base = (((wn >> 4) + nt) * 4 + quad) * 128 + lrow * 8;
            bfh[nt] = *(const bfrag8*)&BhL[base];
            bfl[nt] = *(const bfrag8*)&BlL[base];
        }
        #pragma unroll
        for (int mt = 0; mt < 4; ++mt)
            #pragma unroll
            for (int nt = 0; nt < 4; ++nt) {
                acc[mt][nt] = __builtin_amdgcn_mfma_f32_16x16x32_bf16(
                    afh[mt], bfh[nt], acc[mt][nt], 0, 0, 0);
                acc[mt][nt] = __builtin_amdgcn_mfma_f32_16x16x32_bf16(
                    afh[mt], bfl[nt], acc[mt][nt], 0, 0, 0);
                acc[mt][nt] = __builtin_amdgcn_mfma_f32_16x16x32_bf16(
                    afl[mt], bfh[nt], acc[mt][nt], 0, 0, 0);
            }
    }

    #pragma unroll
    for (int mt = 0; mt < 4; ++mt)
        #pragma unroll
        for (int r = 0; r < 4; ++r) {
            int row = bm + wm + mt * 16 + quad * 4 + r;
            #pragma unroll
            for (int nt = 0; nt < 4; ++nt) {
                int col = bn + wn + nt * 16 + lrow;
                float v = acc[mt][nt][r];
                if (bias)  v += bias[col];
                size_t idx = (size_t)row * N + col;
                if (Ch) {
                    unsigned short hi, lo;
                    split1(v, hi, lo);
                    Ch[idx] = hi; Cl[idx] = lo;
                } else {
                    if (resid) v += resid[idx];
                    C[idx] = v;
                }
            }
        }
}

__global__ __launch_bounds__(256) void gemm_ab_kernel(
    const ushort_t* __restrict__ Ah, const ushort_t* __restrict__ Al,
    const ushort_t* __restrict__ BhT, const ushort_t* __restrict__ BlT,
    const float* __restrict__ bias, const float* __restrict__ resid,
    float* __restrict__ C, int N, int K)
{
    gemm_ab_body(Ah, Al, BhT, BlT, bias, resid, C, nullptr, nullptr, N, K);
}

// QKV: z=0 -> split q (qh,ql); z=1 -> split k (kh,kl); z=2 -> fp32 v
__global__ __launch_bounds__(256) void gemm_qkv_ab_kernel(
    const ushort_t* __restrict__ Ah, const ushort_t* __restrict__ Al,
    const ushort_t* __restrict__ wT,     // 3 weights packed: z*2*S768, hi then lo
    ushort_t* __restrict__ q_h, ushort_t* __restrict__ q_l,
    ushort_t* __restrict__ k_h, ushort_t* __restrict__ k_l,
    float* __restrict__ vf, int N, int K)
{
    const ushort_t* bh = wT + (size_t)blockIdx.z * 2 * S768;
    const ushort_t* bl = bh + S768;
    if (blockIdx.z == 0)
        gemm_ab_body(Ah, Al, bh, bl, nullptr, nullptr, nullptr, q_h, q_l, N, K);
    else if (blockIdx.z == 1)
        gemm_ab_body(Ah, Al, bh, bl, nullptr, nullptr, nullptr, k_h, k_l, N, K);
    else
        gemm_ab_body(Ah, Al, bh, bl, nullptr, nullptr, vf, nullptr, nullptr, N, K);
}

// ---- variant aB32: A pre-split (MxK bf16); B fp32 row-major KxN, split in-kernel ----
__global__ __launch_bounds__(256) void gemm_aB32_kernel(
    const ushort_t* __restrict__ Ah, const ushort_t* __restrict__ Al,
    const float* __restrict__ B, const float* __restrict__ bias,
    const float* __restrict__ resid, float* __restrict__ C,
    ushort_t* __restrict__ Ch, ushort_t* __restrict__ Cl,
    int N, int K, int act)
{
    __shared__ __align__(16) unsigned short AhL[4096];
    __shared__ __align__(16) unsigned short AlL[4096];
    __shared__ __align__(16) unsigned short BhL[4096];
    __shared__ __align__(16) unsigned short BlL[4096];

    const int tid = threadIdx.x;
    const int bm = blockIdx.y * 128, bn = blockIdx.x * 128;
    const int wave = tid >> 6, lane = tid & 63;
    const int wm = (wave >> 1) * 64, wn = (wave & 1) * 64;
    const int lrow = lane & 15, quad = lane >> 4;

    const int sm  = (tid >> 5) * 16 + 2 * (tid & 7);
    const int skq = (tid >> 3) & 3;
    const size_t arow = (size_t)(bm + sm) * K + skq * 8;
    const float* Bbase = B + (size_t)(skq * 8) * N + bn + sm;

    floatx4 acc[4][4];
    #pragma unroll
    for (int i = 0; i < 4; ++i)
        #pragma unroll
        for (int j = 0; j < 4; ++j) acc[i][j] = floatx4{0.f, 0.f, 0.f, 0.f};

    for (int kt = 0; kt < K; kt += 32) {
        bfrag8 a0h = *(const bfrag8*)(Ah + arow + kt);
        bfrag8 a1h = *(const bfrag8*)(Ah + arow + K + kt);
        bfrag8 a0l = *(const bfrag8*)(Al + arow + kt);
        bfrag8 a1l = *(const bfrag8*)(Al + arow + K + kt);
        float2 bv[8];
        #pragma unroll
        for (int j = 0; j < 8; ++j)
            bv[j] = *(const float2*)(Bbase + (size_t)(kt + j) * N);

        __syncthreads();
        *(bfrag8*)&AhL[16 * tid] = a0h;  *(bfrag8*)&AhL[16 * tid + 8] = a1h;
        *(bfrag8*)&AlL[16 * tid] = a0l;  *(bfrag8*)&AlL[16 * tid + 8] = a1l;
        {
            float b0v[8] = {bv[0].x, bv[1].x, bv[2].x, bv[3].x,
                            bv[4].x, bv[5].x, bv[6].x, bv[7].x};
            float b1v[8] = {bv[0].y, bv[1].y, bv[2].y, bv[3].y,
                            bv[4].y, bv[5].y, bv[6].y, bv[7].y};
            split8_store(b0v, &BhL[16 * tid], &BlL[16 * tid]);
            split8_store(b1v, &BhL[16 * tid + 8], &BlL[16 * tid + 8]);
        }
        __syncthreads();

        bfrag8 afh[4], afl[4], bfh[4], bfl[4];
        #pragma unroll
        for (int mt = 0; mt < 4; ++mt) {
            int base = (((wm >> 4) + mt) * 4 + quad) * 128 + lrow * 8;
            afh[mt] = *(const bfrag8*)&AhL[base];
            afl[mt] = *(const bfrag8*)&AlL[base];
        }
        #pragma unroll
        for (int nt = 0; nt < 4; ++nt) {
            int base = (((wn >> 4) + nt) * 4 + quad) * 128 + lrow * 8;
            bfh[nt] = *(const bfrag8*)&BhL[base];
            bfl[nt] = *(const bfrag8*)&BlL[base];
        }
        #pragma unroll
        for (int mt = 0; mt < 4; ++mt)
            #pragma unroll
            for (int nt = 0; nt < 4; ++nt) {
                acc[mt][nt] = __builtin_amdgcn_mfma_f32_16x16x32_bf16(
                    afh[mt], bfh[nt], acc[mt][nt], 0, 0, 0);
                acc[mt][nt] = __builtin_amdgcn_mfma_f32_16x16x32_bf16(
                    afh[mt], bfl[nt], acc[mt][nt], 0, 0, 0);
                acc[mt][nt] = __builtin_amdgcn_mfma_f32_16x16x32_bf16(
                    afl[mt], bfh[nt], acc[mt][nt], 0, 0, 0);
            }
    }

    #pragma unroll
    for (int mt = 0; mt < 4; ++mt)
        #pragma unroll
        for (int r = 0; r < 4; ++r) {
            int row = bm + wm + mt * 16 + quad * 4 + r;
            #pragma unroll
            for (int nt = 0; nt < 4; ++nt) {
                int col = bn + wn + nt * 16 + lrow;
                float v = acc[mt][nt][r];
                if (bias) v += bias[col];
                if (act)  v = 0.5f * v * (1.f + erff(v * 0.70710678118654752f));
                size_t idx = (size_t)row * N + col;
                if (Ch) {
                    unsigned short hi, lo;
                    split1(v, hi, lo);
                    Ch[idx] = hi; Cl[idx] = lo;
                } else {
                    if (resid) v += resid[idx];
                    C[idx] = v;
                }
            }
        }
}

// ---------------- small fp32 GEMM (64x768 ct projection) ----------------
static __device__ __forceinline__ void gemm_body(
    const float* __restrict__ A, const float* __restrict__ B,
    const float* __restrict__ bias, const float* __restrict__ resid,
    float* __restrict__ C, int M, int N, int K, int act)
{
    __shared__ float As[16][128];
    __shared__ float Bs[16][64];
    const int bm = blockIdx.y * 128;
    const int bn = blockIdx.x * 64;
    const int tid = threadIdx.x;
    const int tx = tid & 15;
    const int ty = tid >> 4;
    float acc[8][4];
    #pragma unroll
    for (int i = 0; i < 8; ++i)
        #pragma unroll
        for (int j = 0; j < 4; ++j) acc[i][j] = 0.f;

    const int a_row = tid >> 1;
    const int a_kp  = (tid & 1) * 8;
    const int b_k   = tid >> 4;
    const int b_c   = (tid & 15) * 4;

    for (int k0 = 0; k0 < K; k0 += 16) {
        int grow = bm + a_row;
        float4 a0, a1;
        if (grow < M) {
            const float* ap = A + (size_t)grow * K + (k0 + a_kp);
            a0 = *(const float4*)ap;
            a1 = *(const float4*)(ap + 4);
        } else {
            a0 = make_float4(0.f, 0.f, 0.f, 0.f); a1 = a0;
        }
        float4 bvv = *(const float4*)(B + (size_t)(k0 + b_k) * N + (bn + b_c));
        __syncthreads();
        As[a_kp + 0][a_row] = a0.x; As[a_kp + 1][a_row] = a0.y;
        As[a_kp + 2][a_row] = a0.z; As[a_kp + 3][a_row] = a0.w;
        As[a_kp + 4][a_row] = a1.x; As[a_kp + 5][a_row] = a1.y;
        As[a_kp + 6][a_row] = a1.z; As[a_kp + 7][a_row] = a1.w;
        *(float4*)&Bs[b_k][b_c] = bvv;
        __syncthreads();
        #pragma unroll
        for (int kk = 0; kk < 16; ++kk) {
            float4 af0 = *(const float4*)&As[kk][ty * 8];
            float4 af1 = *(const float4*)&As[kk][ty * 8 + 4];
            float4 bf  = *(const float4*)&Bs[kk][tx * 4];
            float a_[8] = {af0.x, af0.y, af0.z, af0.w, af1.x, af1.y, af1.z, af1.w};
            float b_[4] = {bf.x, bf.y, bf.z, bf.w};
            #pragma unroll
            for (int i = 0; i < 8; ++i)
                #pragma unroll
                for (int j = 0; j < 4; ++j)
                    acc[i][j] = fmaf(a_[i], b_[j], acc[i][j]);
        }
    }
    #pragma unroll
    for (int i = 0; i < 8; ++i) {
        int row = bm + ty * 8 + i;
        if (row < M) {
            #pragma unroll
            for (int j = 0; j < 4; ++j) {
                int col = bn + tx * 4 + j;
                float v = acc[i][j];
                if (bias)  v += bias[col];
                if (act)   v = 0.5f * v * (1.f + erff(v * 0.70710678118654752f));
                if (resid) v += resid[(size_t)row * N + col];
                C[(size_t)row * N + col] = v;
            }
        }
    }
}

__global__ __launch_bounds__(256) void gemm_kernel(
    const float* __restrict__ A, const float* __restrict__ B,
    const float* __restrict__ bias, const float* __restrict__ resid,
    float* __restrict__ C, int M, int N, int K, int act)
{
    gemm_body(A, B, bias, resid, C, M, N, K, act);
}

// ================= MFMA attention =================
// grid (4 q-chunks of 64 rows, 12 heads, 32 batch); 256 thr, wave w = m-tile w.
// Scores: split-bf16 MFMA QK^T from pre-split global q/k; wave-local softmax
// in C-layout; P split hi/lo into LDS [64][224] (zero-padded cols 196..223).
// PV: V (fp32 global) transposed+split on the fly into 32x32 LDS tiles.
__global__ __launch_bounds__(256) void attn_mfma_kernel(
    const ushort_t* __restrict__ qh, const ushort_t* __restrict__ ql,
    const ushort_t* __restrict__ kh, const ushort_t* __restrict__ kl,
    const float* __restrict__ v, ushort_t* __restrict__ oh,
    ushort_t* __restrict__ ol)
{
    __shared__ __align__(16) ushort_t Ph[64 * 224];   // 28672 B
    __shared__ __align__(16) ushort_t Pl[64 * 224];   // 28672 B
    __shared__ __align__(16) ushort_t VTh[32 * 32];   //  2048 B
    __shared__ __align__(16) ushort_t VTl[32 * 32];   //  2048 B   -> 61440 total

    const int tid = threadIdx.x;
    const int w = tid >> 6, lane = tid & 63;
    const int lrow = lane & 15, quad = lane >> 4;
    const int hbase = (int)blockIdx.y * DHEAD;
    const int b = blockIdx.z;
    const int mt = blockIdx.x * 4 + w;                // global m-tile 0..15
    const size_t tok0 = (size_t)b * 196;

    // ---- Q fragments (ks = 0,1), rows clamped to 195 ----
    int qrow = mt * 16 + lrow; if (qrow > 195) qrow = 195;
    const size_t qoff = (tok0 + qrow) * DIM + hbase + quad * 8;
    bfrag8 qfh0 = *(const bfrag8*)(qh + qoff);
    bfrag8 qfh1 = *(const bfrag8*)(qh + qoff + 32);
    bfrag8 qfl0 = *(const bfrag8*)(ql + qoff);
    bfrag8 qfl1 = *(const bfrag8*)(ql + qoff + 32);

    // ---- scores: 13 n-tiles ----
    floatx4 sacc[13];
    #pragma unroll
    for (int nt = 0; nt < 13; ++nt) {
        int krow = nt * 16 + lrow; if (krow > 195) krow = 195;
        const size_t koff = (tok0 + krow) * DIM + hbase + quad * 8;
        bfrag8 kfh0 = *(const bfrag8*)(kh + koff);
        bfrag8 kfh1 = *(const bfrag8*)(kh + koff + 32);
        bfrag8 kfl0 = *(const bfrag8*)(kl + koff);
        bfrag8 kfl1 = *(const bfrag8*)(kl + koff + 32);
        floatx4 a = floatx4{0.f, 0.f, 0.f, 0.f};
        a = __builtin_amdgcn_mfma_f32_16x16x32_bf16(qfh0, kfh0, a, 0, 0, 0);
        a = __builtin_amdgcn_mfma_f32_16x16x32_bf16(qfh0, kfl0, a, 0, 0, 0);
        a = __builtin_amdgcn_mfma_f32_16x16x32_bf16(qfl0, kfh0, a, 0, 0, 0);
        a = __builtin_amdgcn_mfma_f32_16x16x32_bf16(qfh1, kfh1, a, 0, 0, 0);
        a = __builtin_amdgcn_mfma_f32_16x16x32_bf16(qfh1, kfl1, a, 0, 0, 0);
        a = __builtin_amdgcn_mfma_f32_16x16x32_bf16(qfl1, kfh1, a, 0, 0, 0);
        sacc[nt] = a;
    }

    // ---- softmax per row (row = quad*4 + r), cols across 16-lane group ----
    const float scale = 0.125f;
    #pragma unroll
    for (int r = 0; r < 4; ++r) {
        float m = -3.0e38f;
        #pragma unroll
        for (int nt = 0; nt < 13; ++nt) {
            float s = sacc[nt][r] * scale;
            if (nt == 12 && lrow >= 4) s = -1.0e30f;   // cols 196..207 invalid
            sacc[nt][r] = s;
            m = fmaxf(m, s);
        }
        m = fmaxf(m, __shfl_xor(m, 1));
        m = fmaxf(m, __shfl_xor(m, 2));
        m = fmaxf(m, __shfl_xor(m, 4));
        m = fmaxf(m, __shfl_xor(m, 8));
        float l = 0.f;
        #pragma unroll
        for (int nt = 0; nt < 13; ++nt) {
            float e = expf(sacc[nt][r] - m);
            sacc[nt][r] = e;
            l += e;
        }
        l += __shfl_xor(l, 1);
        l += __shfl_xor(l, 2);
        l += __shfl_xor(l, 4);
        l += __shfl_xor(l, 8);
        float inv = 1.f / l;
        int prow = w * 16 + quad * 4 + r;
        #pragma unroll
        for (int nt = 0; nt < 13; ++nt) {
            unsigned short hi, lo;
            split1(sacc[nt][r] * inv, hi, lo);
            int pidx = prow * 224 + nt * 16 + lrow;
            Ph[pidx] = hi; Pl[pidx] = lo;
        }
    }
    // zero-pad cols 196..223 of this wave's 16 rows
    for (int i = lane; i < 16 * 28; i += 64) {
        int rr = i / 28, cc = 196 + i % 28;
        int pidx = (w * 16 + rr) * 224 + cc;
        Ph[pidx] = 0; Pl[pidx] = 0;
    }

    // ---- PV: O[16 x 64] per wave; V staged 32x32 per (ks, dhalf) ----
    floatx4 oacc[4];
    #pragma unroll
    for (int i = 0; i < 4; ++i) oacc[i] = floatx4{0.f, 0.f, 0.f, 0.f};

    for (int ks = 0; ks < 7; ++ks) {
        #pragma unroll
        for (int dh = 0; dh < 2; ++dh) {
            __syncthreads();
            {   // stage VT[32 d][32 k] from fp32 v, transposed + split
                int kloc = tid >> 3;             // 0..31
                int dloc = (tid & 7) * 4;        // 0,4,..,28
                int vrow = ks * 32 + kloc;
                float4 vv = make_float4(0.f, 0.f, 0.f, 0.f);
                if (vrow < 196)
                    vv = *(const float4*)(v + (tok0 + vrow) * DIM + hbase + dh * 32 + dloc);
                float vs[4] = {vv.x, vv.y, vv.z, vv.w};
                #pragma unroll
                for (int i = 0; i < 4; ++i) {
                    unsigned short hi, lo;
                    split1(vs[i], hi, lo);
                    VTh[(dloc + i) * 32 + kloc] = hi;
                    VTl[(dloc + i) * 32 + kloc] = lo;
                }
            }
            __syncthreads();
            bfrag8 pah = *(const bfrag8*)&Ph[(w * 16 + lrow) * 224 + ks * 32 + quad * 8];
            bfrag8 pal = *(const bfrag8*)&Pl[(w * 16 + lrow) * 224 + ks * 32 + quad * 8];
            #pragma unroll
            for (int ntl = 0; ntl < 2; ++ntl) {
                bfrag8 vbh = *(const bfrag8*)&VTh[(ntl * 16 + lrow) * 32 + quad * 8];
                bfrag8 vbl = *(const bfrag8*)&VTl[(ntl * 16 + lrow) * 32 + quad * 8];
                int nt = dh * 2 + ntl;
                oacc[nt] = __builtin_amdgcn_mfma_f32_16x16x32_bf16(pah, vbh, oacc[nt], 0, 0, 0);
                oacc[nt] = __builtin_amdgcn_mfma_f32_16x16x32_bf16(pah, vbl, oacc[nt], 0, 0, 0);
                oacc[nt] = __builtin_amdgcn_mfma_f32_16x16x32_bf16(pal, vbh, oacc[nt], 0, 0, 0);
            }
        }
    }

    // ---- epilogue: split-store O rows < 196 ----
    #pragma unroll
    for (int nt = 0; nt < 4; ++nt)
        #pragma unroll
        for (int r = 0; r < 4; ++r) {
            int row = mt * 16 + quad * 4 + r;
            if (row < 196) {
                int d = nt * 16 + lrow;
                unsigned short hi, lo;
                split1(oacc[nt][r], hi, lo);
                size_t off = (tok0 + row) * DIM + hbase + d;
                oh[off] = hi; ol[off] = lo;
            }
        }
}

// ---------------- k-means ----------------
__global__ __launch_bounds__(256) void transpose_ct(
    const float* __restrict__ C, float* __restrict__ CT)
{
    int i = blockIdx.x * 256 + threadIdx.x;
    if (i < DIM * KC) {
        int d = i / KC, c = i % KC;
        CT[i] = C[(size_t)c * DIM + d];
    }
}

__global__ __launch_bounds__(256) void assign_kernel(
    const float* __restrict__ P, const float* __restrict__ CT,
    const float* __restrict__ cn2, const float* __restrict__ pn2,
    int* __restrict__ labels)
{
    __shared__ float cts[256 * KC];
    int wave = threadIdx.x >> 6, lane = threadIdx.x & 63;
    int p = blockIdx.x * 4 + wave;
    float acc = 0.f;
    for (int ch = 0; ch < 3; ++ch) {
        __syncthreads();
        for (int e = threadIdx.x; e < 256 * KC / 4; e += 256)
            ((float4*)cts)[e] = ((const float4*)(CT + (size_t)ch * 256 * KC))[e];
        __syncthreads();
        const float* pr = P + (size_t)p * DIM + ch * 256;
        float a0 = 0.f, a1 = 0.f, a2 = 0.f, a3 = 0.f;
        #pragma unroll 4
        for (int kk = 0; kk < 256; kk += 4) {
            a0 = fmaf(pr[kk],     cts[(kk)     * KC + lane], a0);
            a1 = fmaf(pr[kk + 1], cts[(kk + 1) * KC + lane], a1);
            a2 = fmaf(pr[kk + 2], cts[(kk + 2) * KC + lane], a2);
            a3 = fmaf(pr[kk + 3], cts[(kk + 3) * KC + lane], a3);
        }
        acc += (a0 + a1) + (a2 + a3);
    }
    float dist = (pn2[p] - 2.f * acc) + cn2[lane];
    int idx = lane;
    #pragma unroll
    for (int off = 32; off > 0; off >>= 1) {
        float d2 = __shfl_xor(dist, off);
        int   i2 = __shfl_xor(idx, off);
        if (d2 < dist || (d2 == dist && i2 < idx)) { dist = d2; idx = i2; }
    }
    if (lane == 0) labels[p] = idx;
}

// counting sort: one block. cnt[c], off[c], stable order[] of point indices.
__global__ __launch_bounds__(256) void order_kernel(
    const int* __restrict__ labels, int* __restrict__ cnt,
    int* __restrict__ off, int* __restrict__ order)
{
    __shared__ int labs[M_TOK];
    __shared__ int hist[4][KC];
    __shared__ int wstart[4][KC];
    int tid = threadIdx.x;
    for (int p = tid; p < M_TOK; p += 256) labs[p] = labels[p];
    int wave = tid >> 6, lane = tid & 63;
    __syncthreads();
    const int base = wave * (M_TOK / 4);
    int h = 0;
    for (int i = 0; i < M_TOK / 4; ++i) h += (labs[base + i] == lane);
    hist[wave][lane] = h;
    __syncthreads();
    if (tid == 0) {
        int run = 0;
        for (int c = 0; c < KC; ++c) {
            int h0 = hist[0][c], h1 = hist[1][c], h2 = hist[2][c], h3 = hist[3][c];
            cnt[c] = h0 + h1 + h2 + h3;
            off[c] = run;
            wstart[0][c] = run;
            wstart[1][c] = run + h0;
            wstart[2][c] = run + h0 + h1;
            wstart[3][c] = run + h0 + h1 + h2;
            run += h0 + h1 + h2 + h3;
        }
    }
    __syncthreads();
    int pos = wstart[wave][lane];
    for (int i = 0; i < M_TOK / 4; ++i) {
        if (labs[base + i] == lane) order[pos++] = base + i;
    }
}

__global__ __launch_bounds__(768) void update_gather_kernel(
    const float* __restrict__ P, const int* __restrict__ order,
    const int* __restrict__ cnt, const int* __restrict__ off,
    const float* __restrict__ cin, float* __restrict__ cout)
{
    __shared__ int rows[M_TOK];
    int c = blockIdx.x;
    int n = cnt[c], o = off[c];
    int d = threadIdx.x;
    for (int i = d; i < n; i += 768) rows[i] = order[o + i];
    __syncthreads();
    float a0 = 0.f, a1 = 0.f, a2 = 0.f, a3 = 0.f;
    int i = 0;
    for (; i + 4 <= n; i += 4) {
        a0 += P[(size_t)rows[i]     * DIM + d];
        a1 += P[(size_t)rows[i + 1] * DIM + d];
        a2 += P[(size_t)rows[i + 2] * DIM + d];
        a3 += P[(size_t)rows[i + 3] * DIM + d];
    }
    for (; i < n; ++i) a0 += P[(size_t)rows[i] * DIM + d];
    float s = (a0 + a1) + (a2 + a3);
    cout[(size_t)c * DIM + d] = (n > 0) ? (s / (float)n) : cin[(size_t)c * DIM + d];
}

__global__ __launch_bounds__(256) void gather_kernel(
    const float* __restrict__ cproj, const int* __restrict__ labels,
    float* __restrict__ out)
{
    int i = blockIdx.x * 256 + threadIdx.x;
    int p = i / DIM, d = i - p * DIM;
    out[i] = cproj[(size_t)labels[p] * DIM + d];
}

// ---------------- host ----------------
extern "C" void kernel_launch(void* const* d_in, const int* in_sizes, int n_in,
                              void* d_out, int out_size, void* d_ws, size_t ws_size,
                              hipStream_t stream)
{
    const float* x    = (const float*)d_in[0];
    const float* ln1w = (const float*)d_in[1];
    const float* ln1b = (const float*)d_in[2];
    const float* wq   = (const float*)d_in[3];
    const float* wk   = (const float*)d_in[4];
    const float* wv   = (const float*)d_in[5];
    const float* wo   = (const float*)d_in[6];
    const float* bo   = (const float*)d_in[7];
    const float* ln2w = (const float*)d_in[8];
    const float* ln2b = (const float*)d_in[9];
    const float* w1   = (const float*)d_in[10];
    const float* b1   = (const float*)d_in[11];
    const float* w2   = (const float*)d_in[12];
    const float* b2   = (const float*)d_in[13];
    const float* ctw  = (const float*)d_in[14];
    const float* ctb  = (const float*)d_in[15];

    const size_t M768 = (size_t)M_TOK * DIM;      // 4,816,896 elements
    float* ws    = (float*)d_ws;
    float* xbuf  = ws;
    float* qbuf  = xbuf + M768;
    float* kbuf  = qbuf + M768;
    float* vbuf  = kbuf + M768;
    float* obuf  = vbuf + M768;
    float* cA    = obuf + M768;
    float* cB    = cA + (size_t)KC * DIM;
    float* CT    = cB + (size_t)KC * DIM;
    float* cproj = CT + (size_t)KC * DIM;
    float* cn2   = cproj + (size_t)KC * DIM;
    float* pn2   = cn2 + KC;
    int*  labels = (int*)(pn2 + M_TOK);
    int*  cnt    = labels + M_TOK;
    int*  coff   = cnt + KC;
    int*  order  = coff + KC;

    // bf16 split aliases (same proven footprint):
    ushort_t* hh    = (ushort_t*)d_out;           // h hi   (M x 768)
    ushort_t* hl    = hh + M768;                  // h lo
    ushort_t* woT   = (ushort_t*)d_out;           // wo^T split (after h consumed)
    ushort_t* wqkvT = (ushort_t*)obuf;            // 3x 768x768 hi/lo (7.1 MB)
    ushort_t* q_h   = (ushort_t*)qbuf;            // q hi/lo in qbuf region
    ushort_t* q_l   = q_h + M768;
    ushort_t* k_h   = (ushort_t*)kbuf;            // k hi/lo in kbuf region
    ushort_t* k_l   = k_h + M768;
    ushort_t* oh    = (ushort_t*)obuf;            // o hi (after wqkvT consumed)
    ushort_t* ol    = oh + M768;                  // o lo
    ushort_t* m1h   = (ushort_t*)qbuf;            // m1 hi (M x 3072) -> q+k region
    ushort_t* m1l   = m1h + (size_t)M_TOK * MLPD; // m1 lo -> v+o region

    hipMemcpyAsync(xbuf, x, M768 * sizeof(float), hipMemcpyDeviceToDevice, stream);

    dim3 blk(256);
    dim3 gN768(DIM / 128, M_TOK / 128);        // 6 x 49
    dim3 gN3072(MLPD / 128, M_TOK / 128);      // 24 x 49
    dim3 gqkv(DIM / 128, M_TOK / 128, 3);      // 6 x 49 x 3
    dim3 gsplit3(DIM / 32, DIM / 32, 3);
    dim3 gsplit1(DIM / 32, DIM / 32, 1);
    dim3 gattn(4, NHEAD, 32);                  // q-chunks x heads x batch

    for (int d = 0; d < 4; ++d) {
        size_t w768 = (size_t)d * DIM * DIM;
        ln_split_kernel<<<M_TOK, blk, 0, stream>>>(xbuf, ln1w + d * DIM, ln1b + d * DIM, hh, hl);
        wsplitT_kernel<<<gsplit3, blk, 0, stream>>>(wq + w768, wk + w768, wv + w768,
                                                    wqkvT, DIM, DIM);
        gemm_qkv_ab_kernel<<<gqkv, blk, 0, stream>>>(hh, hl, wqkvT,
                                                     q_h, q_l, k_h, k_l, vbuf, DIM, DIM);
        attn_mfma_kernel<<<gattn, blk, 0, stream>>>(q_h, q_l, k_h, k_l, vbuf, oh, ol);
        wsplitT_kernel<<<gsplit1, blk, 0, stream>>>(wo + w768, wo + w768, wo + w768,
                                                    woT, DIM, DIM);
        gemm_ab_kernel<<<gN768, blk, 0, stream>>>(oh, ol, woT, woT + S768,
                                                  bo + d * DIM, xbuf, xbuf, DIM, DIM);
        ln_split_kernel<<<M_TOK, blk, 0, stream>>>(xbuf, ln2w + d * DIM, ln2b + d * DIM, hh, hl);
        gemm_aB32_kernel<<<gN3072, blk, 0, stream>>>(hh, hl, w1 + (size_t)d * DIM * MLPD,
                                                     b1 + d * MLPD, nullptr, nullptr,
                                                     m1h, m1l, MLPD, DIM, 1);
        gemm_aB32_kernel<<<gN768, blk, 0, stream>>>(m1h, m1l, w2 + (size_t)d * MLPD * DIM,
                                                    b2 + d * DIM, xbuf, xbuf,
                                                    nullptr, nullptr, DIM, MLPD, 0);
    }

    // ---- k-means on xbuf ----
    rownorm2_kernel<<<M_TOK, blk, 0, stream>>>(xbuf, pn2);
    hipMemcpyAsync(cA, xbuf, (size_t)KC * DIM * sizeof(float),
                   hipMemcpyDeviceToDevice, stream);
    float* cin = cA; float* cout = cB;
    for (int it = 0; it < 10; ++it) {
        rownorm2_kernel<<<KC, blk, 0, stream>>>(cin, cn2);
        transpose_ct<<<(KC * DIM + 255) / 256, blk, 0, stream>>>(cin, CT);
        assign_kernel<<<M_TOK / 4, blk, 0, stream>>>(xbuf, CT, cn2, pn2, labels);
        order_kernel<<<1, blk, 0, stream>>>(labels, cnt, coff, order);
        update_gather_kernel<<<KC, dim3(768), 0, stream>>>(xbuf, order, cnt, coff, cin, cout);
        float* t = cin; cin = cout; cout = t;
    }
    rownorm2_kernel<<<KC, blk, 0, stream>>>(cin, cn2);
    transpose_ct<<<(KC * DIM + 255) / 256, blk, 0, stream>>>(cin, CT);
    assign_kernel<<<M_TOK / 4, blk, 0, stream>>>(xbuf, CT, cn2, pn2, labels);

    gemm_kernel<<<dim3(DIM / 64, 1), blk, 0, stream>>>(cin, ctw, ctb, nullptr, cproj,
                                                       KC, DIM, DIM, 0);
    gather_kernel<<<(M_TOK * DIM) / 256, blk, 0, stream>>>(cproj, labels, (float*)d_out);
}